// Round 11
// baseline (589.817 us; speedup 1.0000x reference)
//
#include <hip/hip_runtime.h>
#include <hip/hip_fp16.h>
#include <hip/hip_bf16.h>

typedef __attribute__((ext_vector_type(8))) short bf16x8;
typedef __attribute__((ext_vector_type(4))) float f32x4;

constexpr int EMBED = 64;
constexpr int RBF   = 16;

__device__ __forceinline__ short f2bf(float f) {
    __hip_bfloat16 h = __float2bfloat16(f);   // RNE
    return *reinterpret_cast<short*>(&h);
}
__device__ __forceinline__ unsigned pk_bf(float lo, float hi) {
    unsigned l = (unsigned short)f2bf(lo);
    unsigned h = (unsigned short)f2bf(hi);
    return l | (h << 16);
}
__device__ __forceinline__ unsigned pk_f16(float lo, float hi) {
    __half2 h = __halves2half2(__float2half_rn(lo), __float2half_rn(hi));
    return *reinterpret_cast<unsigned*>(&h);
}
__device__ __forceinline__ void atom_pk_add_f16(__half* addr, unsigned data) {
    asm volatile("global_atomic_pk_add_f16 %0, %1, off"
                 :: "v"(addr), "v"(data) : "memory");
}
__device__ __forceinline__ float silu(float x) {
    return x * __builtin_amdgcn_rcpf(1.0f + __expf(-x));
}
// channel map (validated r5/r6/r10): lane c, acc t -> channel (t&1)+2c+32(t>>1)
__device__ __forceinline__ int ch_map(int t, int c) {
    return (t & 1) + 2 * c + 32 * (t >> 1);
}

// bf16(pi), bf16(pi/2) — validated r10 (bitwise-identical to the reference
// angle after bf16 quantization; pi/2 for self-loops).
constexpr short BF16_PI  = (short)0x4049;
constexpr short BF16_PI2 = (short)0x3FC9;

// ======================= edge kernel: GEMM1 + SiLU + scatter ===============
// agg = (sum_e silu(h1_e)) @ W2 + deg*b2 commutes W2 out of the edge loop:
// scatter silu(h1) (f16 pk atomics) + deg (1 fp32 atomic/edge). All A1 loads
// hoisted before any atomics so vmcnt waits never drain atomic traffic.
template <bool GUARD>
__global__ __launch_bounds__(256, 2) void edge_sum_kernel(
    const float* __restrict__ rbf,
    const int* __restrict__ ei,
    const float* __restrict__ W1,
    const float* __restrict__ b1,
    __half* __restrict__ ssum,
    float* __restrict__ deg,
    int e_base, int E)
{
    __shared__ int lds_row[256];

    const int tid  = threadIdx.x;
    const int lane = tid & 63;
    const int wave = tid >> 6;
    const int g = lane >> 4;
    const int c = lane & 15;
    const int blk_e0 = e_base + blockIdx.x * 256;

    {
        const int e = blk_e0 + tid;
        const bool v = !GUARD || (e < E);
        const int row = v ? ei[e] : 0;
        lds_row[tid] = row;
        if (v) atomicAdd(&deg[row], 1.0f);
    }
    __syncthreads();

    // ---- GEMM1 B fragments (VGPR-resident) ----
    bf16x8 b1f[4];
    float b1v[4];
#pragma unroll
    for (int t = 0; t < 4; ++t) {
        const int ch = ch_map(t, c);
#pragma unroll
        for (int j = 0; j < 8; ++j) {
            const int k = g * 8 + j;
            b1f[t][j] = (k <= RBF) ? f2bf(W1[k * EMBED + ch]) : (short)0;
        }
        b1v[t] = b1[ch];
    }

    const int e0w = blk_e0 + wave * 64;

    // ---- hoisted A1 builds (all loads precede all atomics) ----
    bf16x8 a1[4];
#pragma unroll
    for (int mt = 0; mt < 4; ++mt) {
        bf16x8 a = {};
        const int e0 = e0w + mt * 16;
        const int ea = e0 + c;
        const bool ev = !GUARD || (ea < E);
        if (g < 2) {
            if (ev) {
                const float4 p0 = *reinterpret_cast<const float4*>(rbf + (long long)ea * RBF + g * 8);
                const float4 p1 = *reinterpret_cast<const float4*>(rbf + (long long)ea * RBF + g * 8 + 4);
                a[0] = f2bf(p0.x); a[1] = f2bf(p0.y); a[2] = f2bf(p0.z); a[3] = f2bf(p0.w);
                a[4] = f2bf(p1.x); a[5] = f2bf(p1.y); a[6] = f2bf(p1.z); a[7] = f2bf(p1.w);
            }
        } else if (g == 2 && ev) {
            const int row = lds_row[wave * 64 + mt * 16 + c];
            const int col = ei[E + ea];
            a[0] = (row == col) ? BF16_PI2 : BF16_PI;
        }
        a1[mt] = a;
    }

    // ---- GEMM1 + SiLU + scatter per tile ----
#pragma unroll
    for (int mt = 0; mt < 4; ++mt) {
        const int e0 = e0w + mt * 16;
        if (GUARD && e0 >= E) break;
        const int el0 = wave * 64 + mt * 16;

        f32x4 s[4];
#pragma unroll
        for (int t = 0; t < 4; ++t) {
            f32x4 ci = {b1v[t], b1v[t], b1v[t], b1v[t]};
            s[t] = __builtin_amdgcn_mfma_f32_16x16x32_bf16(a1[mt], b1f[t], ci, 0, 0, 0);
        }

        // lane holds edge g*4+r, channels ch_map(t,c) -> (2c,2c+1),(32+2c,33+2c)
#pragma unroll
        for (int r = 0; r < 4; ++r) {
            const int eat = e0 + g * 4 + r;
            if (!GUARD || eat < E) {
                const unsigned row = (unsigned)lds_row[el0 + g * 4 + r];
                __half* const dst = ssum + row * 64u;
                atom_pk_add_f16(dst + 2 * c,
                                pk_f16(silu(s[0][r]), silu(s[1][r])));
                atom_pk_add_f16(dst + 32 + 2 * c,
                                pk_f16(silu(s[2][r]), silu(s[3][r])));
            }
        }
    }
}

// ======================= k_agg: agg = ssum @ W2 (fp32) + deg * b2 ==========
__global__ __launch_bounds__(256) void k_agg(
    const __half* __restrict__ ssum, const float* __restrict__ deg,
    const float* __restrict__ W2, const float* __restrict__ b2,
    float* __restrict__ agg, int nn)
{
    __shared__ __align__(16) float lds_s[4][EMBED];
    const int lane = threadIdx.x & 63;
    const int wave = threadIdx.x >> 6;

    float w2c[EMBED];
#pragma unroll
    for (int j = 0; j < EMBED; ++j) w2c[j] = W2[j * EMBED + lane];
    const float b2v = b2[lane];

    const float4* s4 = reinterpret_cast<const float4*>(lds_s[wave]);
    const int wid = blockIdx.x * 4 + wave;
    const int nw  = gridDim.x * 4;
    for (int n = wid; n < nn; n += nw) {
        const long long base = (long long)n * EMBED + lane;
        const float a = __half2float(ssum[base]);

        lds_s[wave][lane] = a;
        __builtin_amdgcn_wave_barrier();

        float acc = deg[n] * b2v;
#pragma unroll
        for (int j4 = 0; j4 < EMBED / 4; ++j4) {
            const float4 sv = s4[j4];
            acc = fmaf(sv.x, w2c[4 * j4 + 0], acc);
            acc = fmaf(sv.y, w2c[4 * j4 + 1], acc);
            acc = fmaf(sv.z, w2c[4 * j4 + 2], acc);
            acc = fmaf(sv.w, w2c[4 * j4 + 3], acc);
        }
        __builtin_amdgcn_wave_barrier();

        agg[base] = acc;
    }
}

// ======================= node kernel (r5/r10-validated, fp32 agg) ==========
__global__ __launch_bounds__(256) void node_kernel(
    const float* __restrict__ x, const float* __restrict__ aggv,
    const float* __restrict__ W3, const float* __restrict__ b3,
    const float* __restrict__ W4, const float* __restrict__ b4,
    float* __restrict__ out, int nn)
{
    __shared__ __align__(16) float lds_s[4][EMBED];
    const int lane = threadIdx.x & 63;
    const int wave = threadIdx.x >> 6;
    float w3c[EMBED], w4c[EMBED];
#pragma unroll
    for (int j = 0; j < EMBED; ++j) w3c[j] = W3[j * EMBED + lane];
#pragma unroll
    for (int j = 0; j < EMBED; ++j) w4c[j] = W4[j * EMBED + lane];
    const float b3v = b3[lane];
    const float b4v = b4[lane];
    const float4* s4 = reinterpret_cast<const float4*>(lds_s[wave]);
    const int wid = blockIdx.x * 4 + wave;
    const int nw  = gridDim.x * 4;
    for (int n = wid; n < nn; n += nw) {
        const long long base = (long long)n * EMBED + lane;
        const float a = aggv[base];
        lds_s[wave][lane] = a;
        __builtin_amdgcn_wave_barrier();
        float acc = b3v;
#pragma unroll
        for (int j4 = 0; j4 < EMBED / 4; ++j4) {
            const float4 sv = s4[j4];
            acc = fmaf(sv.x, w3c[4 * j4 + 0], acc);
            acc = fmaf(sv.y, w3c[4 * j4 + 1], acc);
            acc = fmaf(sv.z, w3c[4 * j4 + 2], acc);
            acc = fmaf(sv.w, w3c[4 * j4 + 3], acc);
        }
        const float s = acc * __builtin_amdgcn_rcpf(1.0f + __expf(-acc));
        __builtin_amdgcn_wave_barrier();
        lds_s[wave][lane] = s;
        __builtin_amdgcn_wave_barrier();
        float acc2 = b4v;
#pragma unroll
        for (int j4 = 0; j4 < EMBED / 4; ++j4) {
            const float4 sv = s4[j4];
            acc2 = fmaf(sv.x, w4c[4 * j4 + 0], acc2);
            acc2 = fmaf(sv.y, w4c[4 * j4 + 1], acc2);
            acc2 = fmaf(sv.z, w4c[4 * j4 + 2], acc2);
            acc2 = fmaf(sv.w, w4c[4 * j4 + 3], acc2);
        }
        __builtin_amdgcn_wave_barrier();
        out[base] = x[base] + acc2;
    }
}

// ======================= fallback (r10-validated fp32 atomic path) =========
__global__ __launch_bounds__(256, 2) void edge_kernel_fb(
    const float* __restrict__ rbf,
    const int* __restrict__ ei,
    const float* __restrict__ W1,
    const float* __restrict__ b1,
    const float* __restrict__ W2,
    const float* __restrict__ b2,
    float* __restrict__ agg,
    int E)
{
    __shared__ __align__(16) short lds_s[4][16 * 64];
    __shared__ int lds_row[256];
    const int tid = threadIdx.x, lane = tid & 63, wave = tid >> 6;
    const int g = lane >> 4, c = lane & 15;
    const int blk_e0 = blockIdx.x * 256;
    {
        const int e = blk_e0 + tid;
        lds_row[tid] = (e < E) ? ei[e] : 0;
    }
    __syncthreads();
    bf16x8 b1f[4];
    float b1v[4], b2v[4];
#pragma unroll
    for (int t = 0; t < 4; ++t) {
        const int ch = ch_map(t, c);
#pragma unroll
        for (int j = 0; j < 8; ++j) {
            const int k = g * 8 + j;
            b1f[t][j] = (k <= RBF) ? f2bf(W1[k * EMBED + ch]) : (short)0;
        }
        b1v[t] = b1[ch];
        b2v[t] = b2[ch];
    }
    bf16x8 b2f[2][4];
#pragma unroll
    for (int kk = 0; kk < 2; ++kk)
#pragma unroll
        for (int t = 0; t < 4; ++t) {
            const int ch = ch_map(t, c);
#pragma unroll
            for (int j = 0; j < 8; ++j)
                b2f[kk][t][j] = f2bf(W2[(kk * 32 + g * 8 + j) * EMBED + ch]);
        }
    char* const sl = reinterpret_cast<char*>(lds_s[wave]);
    const int e0w = blk_e0 + wave * 64;
#pragma unroll 1
    for (int mt = 0; mt < 4; ++mt) {
        const int e0 = e0w + mt * 16;
        if (e0 >= E) break;
        const int el0 = wave * 64 + mt * 16;
        bf16x8 a = {};
        const int ea = e0 + c;
        const bool ev = (ea < E);
        if (g < 2) {
            if (ev) {
                const float4 p0 = *reinterpret_cast<const float4*>(rbf + (long long)ea * RBF + g * 8);
                const float4 p1 = *reinterpret_cast<const float4*>(rbf + (long long)ea * RBF + g * 8 + 4);
                a[0] = f2bf(p0.x); a[1] = f2bf(p0.y); a[2] = f2bf(p0.z); a[3] = f2bf(p0.w);
                a[4] = f2bf(p1.x); a[5] = f2bf(p1.y); a[6] = f2bf(p1.z); a[7] = f2bf(p1.w);
            }
        } else if (g == 2 && ev) {
            const int row = lds_row[el0 + c];
            const int col = ei[E + ea];
            a[0] = (row == col) ? BF16_PI2 : BF16_PI;
        }
        f32x4 acc1[4];
#pragma unroll
        for (int t = 0; t < 4; ++t) {
            f32x4 ci = {b1v[t], b1v[t], b1v[t], b1v[t]};
            acc1[t] = __builtin_amdgcn_mfma_f32_16x16x32_bf16(a, b1f[t], ci, 0, 0, 0);
        }
#pragma unroll
        for (int r = 0; r < 4; ++r) {
            const int erow = g * 4 + r;
            const int swz = (erow & 7) << 4;
            *reinterpret_cast<unsigned*>(sl + erow * 128 + ((4 * c) ^ swz)) =
                pk_bf(silu(acc1[0][r]), silu(acc1[1][r]));
            *reinterpret_cast<unsigned*>(sl + erow * 128 + ((64 + 4 * c) ^ swz)) =
                pk_bf(silu(acc1[2][r]), silu(acc1[3][r]));
        }
        __builtin_amdgcn_wave_barrier();
        bf16x8 a2[2];
#pragma unroll
        for (int kk = 0; kk < 2; ++kk) {
            const int byte = c * 128 + ((kk * 64 + g * 16) ^ ((c & 7) << 4));
            a2[kk] = *reinterpret_cast<const bf16x8*>(sl + byte);
        }
        __builtin_amdgcn_wave_barrier();
        f32x4 acc2[4];
#pragma unroll
        for (int t = 0; t < 4; ++t) {
            f32x4 ci = {b2v[t], b2v[t], b2v[t], b2v[t]};
            acc2[t] = __builtin_amdgcn_mfma_f32_16x16x32_bf16(a2[0], b2f[0][t], ci, 0, 0, 0);
            acc2[t] = __builtin_amdgcn_mfma_f32_16x16x32_bf16(a2[1], b2f[1][t], acc2[t], 0, 0, 0);
        }
#pragma unroll
        for (int r = 0; r < 4; ++r) {
            const int eat = e0 + g * 4 + r;
            if (eat < E) {
                const unsigned row = (unsigned)lds_row[el0 + g * 4 + r];
                float* const dst = agg + row * 64u;
                const int ch0 = 2 * c, ch2 = 32 + 2 * c;
                atomicAdd(dst + ch0,     acc2[0][r]);
                atomicAdd(dst + ch0 + 1, acc2[1][r]);
                atomicAdd(dst + ch2,     acc2[2][r]);
                atomicAdd(dst + ch2 + 1, acc2[3][r]);
            }
        }
    }
}

// ===========================================================================
extern "C" void kernel_launch(void* const* d_in, const int* in_sizes, int n_in,
                              void* d_out, int out_size, void* d_ws, size_t ws_size,
                              hipStream_t stream) {
    const float* x      = (const float*)d_in[0];
    const float* rbf    = (const float*)d_in[2];
    const int*   ei     = (const int*)d_in[3];
    const float* W1 = (const float*)d_in[4];
    const float* b1 = (const float*)d_in[5];
    const float* W2 = (const float*)d_in[6];
    const float* b2 = (const float*)d_in[7];
    const float* W3 = (const float*)d_in[8];
    const float* b3 = (const float*)d_in[9];
    const float* W4 = (const float*)d_in[10];
    const float* b4 = (const float*)d_in[11];
    float* out = (float*)d_out;

    const int E  = (int)(in_sizes[3] / 2);
    const int nn = in_sizes[0] / EMBED;

    // ws layout: ssum f16 [nn*64] | deg f32 [nn] | agg f32 [nn*64]
    const size_t ssumBytes = (size_t)nn * EMBED * sizeof(__half);
    const size_t degBytes  = (size_t)nn * sizeof(float);
    const size_t aggBytes  = (size_t)nn * EMBED * sizeof(float);
    __half* ssum = (__half*)d_ws;
    float*  deg  = (float*)((char*)d_ws + ssumBytes);
    float*  agg  = (float*)((char*)d_ws + ssumBytes + degBytes);
    const size_t needed = ssumBytes + degBytes + aggBytes;

    const int nfull = E / 256;
    const int rem   = E - nfull * 256;

    if (ws_size >= needed) {
        hipMemsetAsync(d_ws, 0, ssumBytes + degBytes, stream);
        if (nfull)
            edge_sum_kernel<false><<<dim3(nfull), dim3(256), 0, stream>>>(
                rbf, ei, W1, b1, ssum, deg, 0, E);
        if (rem)
            edge_sum_kernel<true><<<dim3(1), dim3(256), 0, stream>>>(
                rbf, ei, W1, b1, ssum, deg, nfull * 256, E);
        k_agg<<<dim3(2048), dim3(256), 0, stream>>>(ssum, deg, W2, b2, agg, nn);
        node_kernel<<<dim3(2048), dim3(256), 0, stream>>>(
            x, agg, W3, b3, W4, b4, out, nn);
    } else {
        // fallback: r10-style fp32 atomics into d_out, node MLP in place
        hipMemsetAsync(out, 0, (size_t)nn * EMBED * sizeof(float), stream);
        edge_kernel_fb<<<dim3((unsigned)((E + 255) / 256)), dim3(256), 0, stream>>>(
            rbf, ei, W1, b1, W2, b2, out, E);
        node_kernel<<<dim3(2048), dim3(256), 0, stream>>>(
            x, out, W3, b3, W4, b4, out, nn);
    }
}

// Round 12
// 395.951 us; speedup vs baseline: 1.4896x; 1.4896x over previous
//
#include <hip/hip_runtime.h>
#include <hip/hip_fp16.h>
#include <hip/hip_bf16.h>

typedef __attribute__((ext_vector_type(8)))  short bf16x8;
typedef __attribute__((ext_vector_type(4)))  float f32x4;
typedef __attribute__((ext_vector_type(16))) float f32x16;

constexpr int EMBED = 64;
constexpr int RBF   = 16;

__device__ __forceinline__ short f2bf(float f) {
    __hip_bfloat16 h = __float2bfloat16(f);   // RNE
    return *reinterpret_cast<short*>(&h);
}
__device__ __forceinline__ float bf2f(short s) {
    unsigned u = ((unsigned)(unsigned short)s) << 16;
    return __uint_as_float(u);
}
__device__ __forceinline__ unsigned pk_bf(float lo, float hi) {
    unsigned l = (unsigned short)f2bf(lo);
    unsigned h = (unsigned short)f2bf(hi);
    return l | (h << 16);
}
__device__ __forceinline__ unsigned pk_f16(float lo, float hi) {
    __half2 h = __halves2half2(__float2half_rn(lo), __float2half_rn(hi));
    return *reinterpret_cast<unsigned*>(&h);
}
__device__ __forceinline__ void atom_pk_add_f16(__half* addr, unsigned data) {
    asm volatile("global_atomic_pk_add_f16 %0, %1, off"
                 :: "v"(addr), "v"(data) : "memory");
}
__device__ __forceinline__ float silu(float x) {
    return x * __builtin_amdgcn_rcpf(1.0f + __expf(-x));
}

// bf16(pi), bf16(pi/2) as floats (r10-validated angle constants)
constexpr float PI_BF  = 3.140625f;
constexpr float PI2_BF = 1.5703125f;

// C/D row map for 32x32 MFMA: row = (reg&3) + 8*(reg>>2) + 4*(lane>>5)
__device__ __forceinline__ int crow(int j, int h) {
    return (j & 3) + 8 * (j >> 2) + 4 * h;
}

// ======================= edge kernel, 32x32x16 MFMA ========================
// GEMM1: rbf @ W1[0:16] (K=16), angle folded into bias (+ rare self-loop fix).
// Channel-interleave: accA = channels 2n, accB = channels 2n+1 (n=lane&31)
// -> pk pairs are lane-local for LDS writes and atomics.
template <bool GUARD, bool F16>
__global__ __launch_bounds__(256, 2) void edge_kernel32(
    const float* __restrict__ rbf,
    const int* __restrict__ ei,
    const float* __restrict__ W1,
    const float* __restrict__ b1,
    const float* __restrict__ W2,
    const float* __restrict__ b2,
    void* __restrict__ agg,
    int e_base, int E)
{
    __shared__ __align__(16) short lds_s[4][32 * 64];  // 16 KB: per-wave 32e x 64ch
    __shared__ int lds_row[256];
    __shared__ unsigned char lds_flag[256];
    __shared__ int wave_any[4];

    const int tid  = threadIdx.x;
    const int lane = tid & 63;
    const int wave = tid >> 6;
    const int n = lane & 31;     // channel-pair index / edge index (m)
    const int h = lane >> 5;     // k-half
    const int blk_e0 = e_base + blockIdx.x * 256;

    // ---- stage rows + self-loop flags (coalesced) ----
    {
        const int e = blk_e0 + tid;
        const bool v = !GUARD || (e < E);
        const int row = v ? ei[e] : 0;
        const int col = v ? ei[E + e] : 1;
        lds_row[tid]  = row;
        const bool fl = v && (row == col);
        lds_flag[tid] = fl;
        const unsigned long long m = __ballot(fl);
        if (lane == 0) wave_any[wave] = (m != 0ull);
    }
    __syncthreads();

    // ---- B fragments + folded biases (VGPR-resident) ----
    // B layout (32x32x16): nB = lane&31 -> channel 2n+hh ; k = h*8 + j
    bf16x8 b1f[2];
    float  b1v[2], dlt[2], b2v[2];
#pragma unroll
    for (int hh = 0; hh < 2; ++hh) {
        const int ch = 2 * n + hh;
#pragma unroll
        for (int j = 0; j < 8; ++j)
            b1f[hh][j] = f2bf(W1[(h * 8 + j) * EMBED + ch]);
        const float w16 = bf2f(f2bf(W1[RBF * EMBED + ch]));
        b1v[hh] = b1[ch] + PI_BF * w16;          // angle==pi folded into bias
        dlt[hh] = (PI2_BF - PI_BF) * w16;        // self-loop correction
        b2v[hh] = b2[ch];
    }
    bf16x8 b2f[4][2];                            // [k-step][channel half]
#pragma unroll
    for (int kk = 0; kk < 4; ++kk)
#pragma unroll
        for (int hh = 0; hh < 2; ++hh) {
            const int ch = 2 * n + hh;
#pragma unroll
            for (int j = 0; j < 8; ++j)
                b2f[kk][hh][j] = f2bf(W2[(kk * 16 + h * 8 + j) * EMBED + ch]);
        }

    char* const sl = reinterpret_cast<char*>(lds_s[wave]);

#pragma unroll 1
    for (int mt = 0; mt < 2; ++mt) {
        const int e0  = blk_e0 + wave * 64 + mt * 32;
        if (GUARD && e0 >= E) break;
        const int el0 = wave * 64 + mt * 32;

        // ---- A1: edge m=n, k = h*8+j -> rbf[e0+n][h*8 .. h*8+8) ----
        bf16x8 a1 = {};
        {
            const int ea = e0 + n;
            if (!GUARD || ea < E) {
                const float4 p0 = *reinterpret_cast<const float4*>(rbf + (long long)ea * RBF + h * 8);
                const float4 p1 = *reinterpret_cast<const float4*>(rbf + (long long)ea * RBF + h * 8 + 4);
                a1[0] = f2bf(p0.x); a1[1] = f2bf(p0.y); a1[2] = f2bf(p0.z); a1[3] = f2bf(p0.w);
                a1[4] = f2bf(p1.x); a1[5] = f2bf(p1.y); a1[6] = f2bf(p1.z); a1[7] = f2bf(p1.w);
            }
        }

        // ---- GEMM1 (one MFMA per channel half), bias-initialized ----
        f32x16 accA, accB;
#pragma unroll
        for (int j = 0; j < 16; ++j) { accA[j] = b1v[0]; accB[j] = b1v[1]; }
        accA = __builtin_amdgcn_mfma_f32_32x32x16_bf16(a1, b1f[0], accA, 0, 0, 0);
        accB = __builtin_amdgcn_mfma_f32_32x32x16_bf16(a1, b1f[1], accB, 0, 0, 0);

        // ---- rare self-loop correction ----
        if (wave_any[wave]) {
#pragma unroll
            for (int j = 0; j < 16; ++j) {
                const int m = crow(j, h);
                if (lds_flag[el0 + m]) { accA[j] += dlt[0]; accB[j] += dlt[1]; }
            }
        }

        // ---- SiLU + pk-bf16 swizzled LDS write ----
        // edge m = crow(j,h), channel-pair byte 4n ; swz = (m&7)<<4
#pragma unroll
        for (int j = 0; j < 16; ++j) {
            const int m = crow(j, h);
            const unsigned u = pk_bf(silu(accA[j]), silu(accB[j]));
            *reinterpret_cast<unsigned*>(sl + m * 128 + ((4 * n) ^ ((m & 7) << 4))) = u;
        }
        __builtin_amdgcn_wave_barrier();

        // ---- GEMM2: A2 streamed from LDS (shared by both halves) ----
        f32x16 acc2A, acc2B;
#pragma unroll
        for (int j = 0; j < 16; ++j) { acc2A[j] = b2v[0]; acc2B[j] = b2v[1]; }
#pragma unroll
        for (int kk = 0; kk < 4; ++kk) {
            // lane's edge m=n, channels [kk*16 + h*8, +8) -> bytes kk*32+h*16
            const int byte = n * 128 + ((kk * 32 + h * 16) ^ ((n & 7) << 4));
            const bf16x8 a2 = *reinterpret_cast<const bf16x8*>(sl + byte);
            acc2A = __builtin_amdgcn_mfma_f32_32x32x16_bf16(a2, b2f[kk][0], acc2A, 0, 0, 0);
            acc2B = __builtin_amdgcn_mfma_f32_32x32x16_bf16(a2, b2f[kk][1], acc2B, 0, 0, 0);
        }
        __builtin_amdgcn_wave_barrier();   // WAR vs next tile's writes

        // ---- scatter: slot j -> edge crow(j,h); 32 lanes/half cover the
        //      edge's full 128-B row with consecutive pk atomics ----
#pragma unroll
        for (int j = 0; j < 16; ++j) {
            const int m = crow(j, h);
            const int eat = e0 + m;
            if (!GUARD || eat < E) {
                const unsigned row = (unsigned)lds_row[el0 + m];
                if (F16) {
                    __half* const dst = reinterpret_cast<__half*>(agg) + row * 64u;
                    atom_pk_add_f16(dst + 2 * n, pk_f16(acc2A[j], acc2B[j]));
                } else {
                    float* const dst = reinterpret_cast<float*>(agg) + row * 64u;
                    atomicAdd(dst + 2 * n,     acc2A[j]);
                    atomicAdd(dst + 2 * n + 1, acc2B[j]);
                }
            }
        }
    }
}

// ======================= node kernel (r5/r10-validated) ====================
template <bool F16>
__global__ __launch_bounds__(256) void node_kernel(
    const float* __restrict__ x, const void* __restrict__ aggv,
    const float* __restrict__ W3, const float* __restrict__ b3,
    const float* __restrict__ W4, const float* __restrict__ b4,
    float* __restrict__ out, int nn)
{
    __shared__ __align__(16) float lds_s[4][EMBED];
    const int lane = threadIdx.x & 63;
    const int wave = threadIdx.x >> 6;
    float w3c[EMBED], w4c[EMBED];
#pragma unroll
    for (int j = 0; j < EMBED; ++j) w3c[j] = W3[j * EMBED + lane];
#pragma unroll
    for (int j = 0; j < EMBED; ++j) w4c[j] = W4[j * EMBED + lane];
    const float b3v = b3[lane];
    const float b4v = b4[lane];
    const float4* s4 = reinterpret_cast<const float4*>(lds_s[wave]);
    const int wid = blockIdx.x * 4 + wave;
    const int nw  = gridDim.x * 4;
    for (int n = wid; n < nn; n += nw) {
        const long long base = (long long)n * EMBED + lane;
        float a;
        if (F16) a = __half2float(reinterpret_cast<const __half*>(aggv)[base]);
        else     a = reinterpret_cast<const float*>(aggv)[base];
        lds_s[wave][lane] = a;
        __builtin_amdgcn_wave_barrier();
        float acc = b3v;
#pragma unroll
        for (int j4 = 0; j4 < EMBED / 4; ++j4) {
            const float4 sv = s4[j4];
            acc = fmaf(sv.x, w3c[4 * j4 + 0], acc);
            acc = fmaf(sv.y, w3c[4 * j4 + 1], acc);
            acc = fmaf(sv.z, w3c[4 * j4 + 2], acc);
            acc = fmaf(sv.w, w3c[4 * j4 + 3], acc);
        }
        const float s = acc * __builtin_amdgcn_rcpf(1.0f + __expf(-acc));
        __builtin_amdgcn_wave_barrier();
        lds_s[wave][lane] = s;
        __builtin_amdgcn_wave_barrier();
        float acc2 = b4v;
#pragma unroll
        for (int j4 = 0; j4 < EMBED / 4; ++j4) {
            const float4 sv = s4[j4];
            acc2 = fmaf(sv.x, w4c[4 * j4 + 0], acc2);
            acc2 = fmaf(sv.y, w4c[4 * j4 + 1], acc2);
            acc2 = fmaf(sv.z, w4c[4 * j4 + 2], acc2);
            acc2 = fmaf(sv.w, w4c[4 * j4 + 3], acc2);
        }
        __builtin_amdgcn_wave_barrier();
        out[base] = x[base] + acc2;
    }
}

// ===========================================================================
extern "C" void kernel_launch(void* const* d_in, const int* in_sizes, int n_in,
                              void* d_out, int out_size, void* d_ws, size_t ws_size,
                              hipStream_t stream) {
    const float* x      = (const float*)d_in[0];
    const float* rbf    = (const float*)d_in[2];
    const int*   ei     = (const int*)d_in[3];
    const float* W1 = (const float*)d_in[4];
    const float* b1 = (const float*)d_in[5];
    const float* W2 = (const float*)d_in[6];
    const float* b2 = (const float*)d_in[7];
    const float* W3 = (const float*)d_in[8];
    const float* b3 = (const float*)d_in[9];
    const float* W4 = (const float*)d_in[10];
    const float* b4 = (const float*)d_in[11];
    float* out = (float*)d_out;

    const int E  = (int)(in_sizes[3] / 2);
    const int nn = in_sizes[0] / EMBED;

    void* agg16 = d_ws;
    const size_t neededF16 = (size_t)nn * EMBED * sizeof(__half);

    const int nfull = E / 256;
    const int rem   = E - nfull * 256;

    if (ws_size >= neededF16) {
        hipMemsetAsync(agg16, 0, neededF16, stream);
        if (nfull)
            edge_kernel32<false, true><<<dim3(nfull), dim3(256), 0, stream>>>(
                rbf, ei, W1, b1, W2, b2, agg16, 0, E);
        if (rem)
            edge_kernel32<true, true><<<dim3(1), dim3(256), 0, stream>>>(
                rbf, ei, W1, b1, W2, b2, agg16, nfull * 256, E);
        node_kernel<true><<<dim3(2048), dim3(256), 0, stream>>>(
            x, agg16, W3, b3, W4, b4, out, nn);
    } else {
        // fallback: fp32 atomics into d_out, node MLP in place
        hipMemsetAsync(out, 0, (size_t)nn * EMBED * sizeof(float), stream);
        if (nfull)
            edge_kernel32<false, false><<<dim3(nfull), dim3(256), 0, stream>>>(
                rbf, ei, W1, b1, W2, b2, out, 0, E);
        if (rem)
            edge_kernel32<true, false><<<dim3(1), dim3(256), 0, stream>>>(
                rbf, ei, W1, b1, W2, b2, out, nfull * 256, E);
        node_kernel<false><<<dim3(2048), dim3(256), 0, stream>>>(
            x, out, W3, b3, W4, b4, out, nn);
    }
}